// Round 1
// baseline (4892.862 us; speedup 1.0000x reference)
//
#include <hip/hip_runtime.h>
#include <cstdint>
#include <cstddef>

// Problem constants
#define BB     8
#define DIMC   512
#define LL     4096
#define POSN   (BB*LL)        // 32768
#define NG     2
#define NQ     8
#define CS     1024
#define DG     256

// d_out layout (floats): q [8*512*4096] | indices [2*8*4096*8] | losses [16]
#define Q_OFF    0
#define IDX_OFF  16777216
#define LOSS_OFF 17301504

// d_ws layout (floats)
#define OFF_WFT   0               // [1536][512]
#define OFF_BF    786432          // [512]
#define OFF_C2    786944          // [16][1024]
#define OFF_QOUT  803328          // [32768][512]
#define OFF_CANDD 17580544        // [32768][8] float
#define OFF_CANDI 17842688        // [32768][8] int
#define OFF_LOSSP 18104832        // [16][1024]
// total 18121216 floats = 72.5 MB

// ---------------------------------------------------------------------------
// Fuse conv_enc weights with pre_w:  Wf_t[ik][dd] = sum_j cw[j][i][k]*prew[dd][j]
// C = (cw^T) * (prew^T), M=1536 (ik), N=512 (dd), K=512 (j)
__global__ __launch_bounds__(256) void k_fuse_w(const float* __restrict__ cw,
                                               const float* __restrict__ prew,
                                               float* __restrict__ wft) {
    __shared__ __align__(16) float As[16][68];  // As[k][ik]
    __shared__ __align__(16) float Bs[16][68];  // Bs[k][dd]
    int bid = blockIdx.x;
    int mt = bid >> 3, nt = bid & 7;            // 24 x 8
    int m0 = mt * 64, n0 = nt * 64;
    int t = threadIdx.x, tx = t & 15, ty = t >> 4;
    float acc[4][4] = {};
    for (int k0 = 0; k0 < 512; k0 += 16) {
        // A: cw[(k0+kk)*1536 + m0+mm]  (ik contiguous)
        for (int u = t; u < 16 * 64; u += 256) {
            int kk = u >> 6, mm = u & 63;
            As[kk][mm] = cw[(size_t)(k0 + kk) * 1536 + m0 + mm];
        }
        // B: prew[(n0+r)*512 + k0 + ...] stored transposed
        {
            int r = t >> 2, c4 = t & 3;
            float4 v = *(const float4*)&prew[(size_t)(n0 + r) * 512 + k0 + c4 * 4];
            Bs[c4 * 4 + 0][r] = v.x; Bs[c4 * 4 + 1][r] = v.y;
            Bs[c4 * 4 + 2][r] = v.z; Bs[c4 * 4 + 3][r] = v.w;
        }
        __syncthreads();
#pragma unroll
        for (int k = 0; k < 16; ++k) {
            float4 a = *(const float4*)&As[k][ty * 4];  // m from ty
            float4 b = *(const float4*)&Bs[k][tx * 4];  // n from tx
            float av[4] = {a.x, a.y, a.z, a.w}, bv[4] = {b.x, b.y, b.z, b.w};
#pragma unroll
            for (int i = 0; i < 4; ++i)
#pragma unroll
                for (int j = 0; j < 4; ++j) acc[i][j] += av[i] * bv[j];
        }
        __syncthreads();
    }
#pragma unroll
    for (int i = 0; i < 4; ++i) {
        float4 v = {acc[i][0], acc[i][1], acc[i][2], acc[i][3]};
        *(float4*)&wft[(size_t)(m0 + ty * 4 + i) * 512 + n0 + tx * 4] = v;
    }
}

// Fused bias: bf[dd] = preb[dd] + sum_j prew[dd][j]*ceb[j]
__global__ void k_bias(const float* __restrict__ prew, const float* __restrict__ preb,
                       const float* __restrict__ ceb, float* __restrict__ bf) {
    int dd = blockIdx.x * 256 + threadIdx.x;
    if (dd < 512) {
        float s = preb[dd];
        for (int j = 0; j < 512; ++j) s += prew[(size_t)dd * 512 + j] * ceb[j];
        bf[dd] = s;
    }
}

// c2[row] = sum_d cb[row][d]^2, row over [16][1024]
__global__ void k_c2(const float* __restrict__ cb, float* __restrict__ c2) {
    int wave = threadIdx.x >> 6, lane = threadIdx.x & 63;
    int row = blockIdx.x * 4 + wave;  // < 16384
    const float* r = cb + (size_t)row * 256;
    float4 v = *(const float4*)&r[lane * 4];
    float s = v.x * v.x + v.y * v.y + v.z * v.z + v.w * v.w;
#pragma unroll
    for (int m = 1; m < 64; m <<= 1) s += __shfl_xor(s, m);
    if (lane == 0) c2[row] = s;
}

// Fused conv1d(k=3) + pre-linear: h[pos][dd] = bf[dd] + sum_{i,k} Wf_t[i*3+k][dd]*x[b][i][l+k-1]
__global__ __launch_bounds__(256) void k_conv(const float* __restrict__ x,
                                              const float* __restrict__ wft,
                                              const float* __restrict__ bf,
                                              float* __restrict__ h) {
    int bid = blockIdx.x;              // 4096 = dt(8) * b(8) * lt(64)
    int dt = bid >> 9;
    int rem = bid & 511;
    int bb = rem >> 6, lt = rem & 63;
    int l0 = lt * 64, d0 = dt * 64;
    int t = threadIdx.x, tx = t & 15, ty = t >> 4;  // tx->dd, ty->l
    __shared__ float Xs[8][68];
    __shared__ __align__(16) float Ws[24][64];
    float acc[4][4] = {};   // [jl][jd]
    const float* xb = x + (size_t)bb * 512 * 4096;
    for (int i0 = 0; i0 < 512; i0 += 8) {
        for (int u = t; u < 8 * 66; u += 256) {
            int ii = u / 66, c = u % 66;
            int gl = l0 + c - 1;
            Xs[ii][c] = (gl >= 0 && gl < 4096) ? xb[(size_t)(i0 + ii) * 4096 + gl] : 0.f;
        }
        for (int u = t; u < 24 * 64; u += 256) {
            int r = u >> 6, c = u & 63;
            Ws[r][c] = wft[(size_t)(i0 * 3 + r) * 512 + d0 + c];
        }
        __syncthreads();
#pragma unroll
        for (int ii = 0; ii < 8; ++ii) {
            float a[6];
#pragma unroll
            for (int j = 0; j < 6; ++j) a[j] = Xs[ii][ty * 4 + j];
#pragma unroll
            for (int k = 0; k < 3; ++k) {
                float4 b = *(const float4*)&Ws[ii * 3 + k][tx * 4];
                float bv[4] = {b.x, b.y, b.z, b.w};
#pragma unroll
                for (int jl = 0; jl < 4; ++jl)
#pragma unroll
                    for (int jd = 0; jd < 4; ++jd) acc[jl][jd] += a[jl + k] * bv[jd];
            }
        }
        __syncthreads();
    }
    int posb = bb * 4096 + l0 + ty * 4;
    const float4 bias = *(const float4*)&bf[d0 + tx * 4];
#pragma unroll
    for (int jl = 0; jl < 4; ++jl) {
        float4 v = {acc[jl][0] + bias.x, acc[jl][1] + bias.y,
                    acc[jl][2] + bias.z, acc[jl][3] + bias.w};
        *(float4*)&h[(size_t)(posb + jl) * 512 + d0 + tx * 4] = v;
    }
}

// dots GEMM + per-tile argmin: tile 128 pos x 128 codes, K=256
// dist[p][c] = c2[c] - 2 * dot(residual[p], cb[c]); writes per-(pos, ntile) candidate
__global__ __launch_bounds__(256) void k_dots(const float* __restrict__ hres,
                                              const float* __restrict__ cb,
                                              const float* __restrict__ c2,
                                              float* __restrict__ candd,
                                              int* __restrict__ candi,
                                              int q, int g) {
    __shared__ __align__(16) float As[16][132];
    __shared__ __align__(16) float Bs[16][132];
    __shared__ float Dd[16][128];
    __shared__ int   Di[16][128];
    int bid = blockIdx.x;             // 2048 = mt(256) * nt(8)
    int mt = bid >> 3, nt = bid & 7;
    int p0 = mt * 128, n0 = nt * 128;
    int t = threadIdx.x, pt = t & 15, ct = t >> 4;
    const float* cbq = cb + (size_t)(q * 2 + g) * 1024 * 256;
    const float* c2q = c2 + (q * 2 + g) * 1024;
    float acc[8][8] = {};
    for (int k0 = 0; k0 < 256; k0 += 16) {
        for (int u = t; u < 128 * 4; u += 256) {
            int r = u >> 2, c4 = u & 3;
            float4 v = *(const float4*)&hres[(size_t)(p0 + r) * 512 + g * 256 + k0 + c4 * 4];
            As[c4 * 4 + 0][r] = v.x; As[c4 * 4 + 1][r] = v.y;
            As[c4 * 4 + 2][r] = v.z; As[c4 * 4 + 3][r] = v.w;
        }
        for (int u = t; u < 128 * 4; u += 256) {
            int r = u >> 2, c4 = u & 3;
            float4 v = *(const float4*)&cbq[(size_t)(n0 + r) * 256 + k0 + c4 * 4];
            Bs[c4 * 4 + 0][r] = v.x; Bs[c4 * 4 + 1][r] = v.y;
            Bs[c4 * 4 + 2][r] = v.z; Bs[c4 * 4 + 3][r] = v.w;
        }
        __syncthreads();
#pragma unroll
        for (int k = 0; k < 16; ++k) {
            float4 a0 = *(const float4*)&As[k][pt * 8];
            float4 a1 = *(const float4*)&As[k][pt * 8 + 4];
            float4 b0 = *(const float4*)&Bs[k][ct * 8];
            float4 b1 = *(const float4*)&Bs[k][ct * 8 + 4];
            float av[8] = {a0.x, a0.y, a0.z, a0.w, a1.x, a1.y, a1.z, a1.w};
            float bv[8] = {b0.x, b0.y, b0.z, b0.w, b1.x, b1.y, b1.z, b1.w};
#pragma unroll
            for (int i = 0; i < 8; ++i)
#pragma unroll
                for (int j = 0; j < 8; ++j) acc[i][j] += av[i] * bv[j];
        }
        __syncthreads();
    }
    // per-thread argmin over its 8 codes (ascending c; strict < keeps first occurrence)
#pragma unroll
    for (int i = 0; i < 8; ++i) {
        float bd = 1e30f; int bi = 0x7fffffff;
#pragma unroll
        for (int j = 0; j < 8; ++j) {
            int c = n0 + ct * 8 + j;
            float d = c2q[c] - 2.f * acc[i][j];
            if (d < bd) { bd = d; bi = c; }
        }
        Dd[ct][pt * 8 + i] = bd;
        Di[ct][pt * 8 + i] = bi;
    }
    __syncthreads();
    if (t < 128) {
        float bd = Dd[0][t]; int bi = Di[0][t];
#pragma unroll
        for (int j = 1; j < 16; ++j) {
            float d = Dd[j][t]; int i2 = Di[j][t];
            if (d < bd || (d == bd && i2 < bi)) { bd = d; bi = i2; }
        }
        candd[(size_t)(p0 + t) * 8 + nt] = bd;
        candi[(size_t)(p0 + t) * 8 + nt] = bi;
    }
}

// finalize one VQ step: reduce candidates -> idx, gather code, update residual/qout,
// accumulate commit loss, write index (as float) to d_out
__global__ __launch_bounds__(256) void k_fin(float* __restrict__ hres,
                                             const float* __restrict__ cb,
                                             const float* __restrict__ candd,
                                             const int* __restrict__ candi,
                                             float* __restrict__ qout,
                                             float* __restrict__ lossp,
                                             float* __restrict__ idx_out,
                                             int q, int g) {
    int t = threadIdx.x, wave = t >> 6, lane = t & 63;
    const float* cbq = cb + (size_t)(q * 2 + g) * 1024 * 256;
    float lsum = 0.f;
    int pbase = blockIdx.x * 32 + wave * 8;   // grid 1024, 32 pos/block
    for (int i = 0; i < 8; ++i) {
        int pos = pbase + i;
        float bd; int bi;
        if (lane < 8) { bd = candd[(size_t)pos * 8 + lane]; bi = candi[(size_t)pos * 8 + lane]; }
        else          { bd = 1e30f; bi = 0x7fffffff; }
#pragma unroll
        for (int m = 1; m < 8; m <<= 1) {
            float d2 = __shfl_xor(bd, m);
            int   i2 = __shfl_xor(bi, m);
            if (d2 < bd || (d2 == bd && i2 < bi)) { bd = d2; bi = i2; }
        }
        int idx = __shfl(bi, 0);
        float4 cv = *(const float4*)&cbq[(size_t)idx * 256 + lane * 4];
        size_t ro = (size_t)pos * 512 + g * 256 + lane * 4;
        float4 rv = *(const float4*)&hres[ro];
        float4 rn = {rv.x - cv.x, rv.y - cv.y, rv.z - cv.z, rv.w - cv.w};
        *(float4*)&hres[ro] = rn;
        if (q == 0) {
            *(float4*)&qout[ro] = cv;
        } else {
            float4 qv = *(const float4*)&qout[ro];
            qv.x += cv.x; qv.y += cv.y; qv.z += cv.z; qv.w += cv.w;
            *(float4*)&qout[ro] = qv;
        }
        lsum += rn.x * rn.x + rn.y * rn.y + rn.z * rn.z + rn.w * rn.w;
        if (lane == 0)
            idx_out[(size_t)(g * 32768 + pos) * 8 + q] = (float)idx;
    }
#pragma unroll
    for (int m = 1; m < 64; m <<= 1) lsum += __shfl_xor(lsum, m);
    __shared__ float ls[4];
    if (lane == 0) ls[wave] = lsum;
    __syncthreads();
    if (t == 0) lossp[(size_t)(g * 8 + q) * 1024 + blockIdx.x] = ls[0] + ls[1] + ls[2] + ls[3];
}

// post-linear with transposed store: out[b][dd][l] = postb[dd] + sum_j postw[dd][j]*qout[pos][j]
__global__ __launch_bounds__(256) void k_post(const float* __restrict__ qout,
                                              const float* __restrict__ pw,
                                              const float* __restrict__ pb,
                                              float* __restrict__ out) {
    __shared__ __align__(16) float As[16][68];  // As[k][pos]
    __shared__ __align__(16) float Bs[16][68];  // Bs[k][dd]
    int bid = blockIdx.x;            // 4096 = mt(512) * nt(8)
    int mt = bid >> 3, nt = bid & 7;
    int p0 = mt * 64, d0 = nt * 64;
    int t = threadIdx.x, tx = t & 15, ty = t >> 4;  // tx->pos (coalesced store), ty->dd
    float acc[4][4] = {};   // [pos_i][dd_j]
    for (int k0 = 0; k0 < 512; k0 += 16) {
        int r = t >> 2, c4 = t & 3;
        {
            float4 v = *(const float4*)&qout[(size_t)(p0 + r) * 512 + k0 + c4 * 4];
            As[c4 * 4 + 0][r] = v.x; As[c4 * 4 + 1][r] = v.y;
            As[c4 * 4 + 2][r] = v.z; As[c4 * 4 + 3][r] = v.w;
        }
        {
            float4 v = *(const float4*)&pw[(size_t)(d0 + r) * 512 + k0 + c4 * 4];
            Bs[c4 * 4 + 0][r] = v.x; Bs[c4 * 4 + 1][r] = v.y;
            Bs[c4 * 4 + 2][r] = v.z; Bs[c4 * 4 + 3][r] = v.w;
        }
        __syncthreads();
#pragma unroll
        for (int k = 0; k < 16; ++k) {
            float4 a = *(const float4*)&As[k][tx * 4];
            float4 b = *(const float4*)&Bs[k][ty * 4];
            float av[4] = {a.x, a.y, a.z, a.w}, bv[4] = {b.x, b.y, b.z, b.w};
#pragma unroll
            for (int i = 0; i < 4; ++i)
#pragma unroll
                for (int j = 0; j < 4; ++j) acc[i][j] += av[i] * bv[j];
        }
        __syncthreads();
    }
    int bb = p0 >> 12, l0 = p0 & 4095;
#pragma unroll
    for (int jd = 0; jd < 4; ++jd) {
        int dd = d0 + ty * 4 + jd;
        float bias = pb[dd];
        float4 v = {acc[0][jd] + bias, acc[1][jd] + bias,
                    acc[2][jd] + bias, acc[3][jd] + bias};
        *(float4*)&out[((size_t)bb * 512 + dd) * 4096 + l0 + tx * 4] = v;
    }
}

__global__ void k_lossfin(const float* __restrict__ lossp, float* __restrict__ out) {
    int gq = blockIdx.x;   // 16 blocks
    float s = 0.f;
    for (int u = threadIdx.x; u < 1024; u += 256) s += lossp[(size_t)gq * 1024 + u];
    int wave = threadIdx.x >> 6, lane = threadIdx.x & 63;
#pragma unroll
    for (int m = 1; m < 64; m <<= 1) s += __shfl_xor(s, m);
    __shared__ float sh[4];
    if (lane == 0) sh[wave] = s;
    __syncthreads();
    if (threadIdx.x == 0)
        out[gq] = (sh[0] + sh[1] + sh[2] + sh[3]) * (1.f / (8.f * 4096.f * 256.f));
}

extern "C" void kernel_launch(void* const* d_in, const int* in_sizes, int n_in,
                              void* d_out, int out_size, void* d_ws, size_t ws_size,
                              hipStream_t stream) {
    (void)in_sizes; (void)n_in; (void)out_size; (void)ws_size;
    const float* x     = (const float*)d_in[0];
    const float* cew   = (const float*)d_in[1];
    const float* ceb   = (const float*)d_in[2];
    const float* prew  = (const float*)d_in[3];
    const float* preb  = (const float*)d_in[4];
    const float* cb    = (const float*)d_in[5];
    const float* postw = (const float*)d_in[6];
    const float* postb = (const float*)d_in[7];
    // d_in[8], d_in[9]: conv_dec weights — result discarded by reference, skip.

    float* out = (float*)d_out;
    float* ws  = (float*)d_ws;
    float* wft   = ws + OFF_WFT;
    float* bf    = ws + OFF_BF;
    float* c2    = ws + OFF_C2;
    float* qout  = ws + OFF_QOUT;
    float* candd = ws + OFF_CANDD;
    int*   candi = (int*)(ws + OFF_CANDI);
    float* lossp = ws + OFF_LOSSP;
    float* h = out;  // q-region of d_out doubles as residual scratch; overwritten by k_post

    k_fuse_w<<<192, 256, 0, stream>>>(cew, prew, wft);
    k_bias<<<2, 256, 0, stream>>>(prew, preb, ceb, bf);
    k_c2<<<4096, 256, 0, stream>>>(cb, c2);
    k_conv<<<4096, 256, 0, stream>>>(x, wft, bf, h);
    for (int q = 0; q < 8; ++q) {
        for (int g = 0; g < 2; ++g) {
            k_dots<<<2048, 256, 0, stream>>>(h, cb, c2, candd, candi, q, g);
            k_fin<<<1024, 256, 0, stream>>>(h, cb, candd, candi, qout, lossp,
                                            out + IDX_OFF, q, g);
        }
    }
    k_post<<<4096, 256, 0, stream>>>(qout, postw, postb, out);
    k_lossfin<<<16, 256, 0, stream>>>(lossp, out + LOSS_OFF);
}